// Round 1
// baseline (1896.887 us; speedup 1.0000x reference)
//
#include <hip/hip_runtime.h>
#include <math.h>

#define Bd 2
#define Sd 2048
#define Ed 1024
#define Hd 16
#define Dd 64

// ---------------------------------------------------------------------------
// GEMM: Y = X @ W + bias.  X:[M,K] row-major, W:[K,N] row-major.
// split==1: store to head-split layout [B,H,S,D] (n -> h*64+d, m -> b*S+s)
// split==0: store flat Y[m*N+n]
// Tiles: BM=BN=64, BK=16, 256 threads, 4x4 micro-tile per thread.
// ---------------------------------------------------------------------------
__global__ __launch_bounds__(256) void gemm_bias_k(
    const float* __restrict__ X, const float* __restrict__ W,
    const float* __restrict__ bias, float* __restrict__ Y,
    int M, int N, int K, int split)
{
    __shared__ float Xs[16][68];   // [k][m], padded: rows 16B-aligned, conflicts <=2-way
    __shared__ float Ws[16][64];   // [k][n]

    const int tid = threadIdx.x;
    const int m0 = blockIdx.y * 64;
    const int n0 = blockIdx.x * 64;
    const int tx = tid & 15, ty = tid >> 4;

    const int xi = tid >> 2;         // X-tile row 0..63
    const int xj = (tid & 3) * 4;    // X-tile col start (float4)
    const int wj = tid >> 6;         // W-tile row group 0..3
    const int wi = tid & 63;         // W-tile col

    float acc[4][4] = {{0.f}};

    for (int k0 = 0; k0 < K; k0 += 16) {
        // stage X tile 64x16 (transposed into LDS)
        float4 xv = *(const float4*)(X + (size_t)(m0 + xi) * K + k0 + xj);
        Xs[xj + 0][xi] = xv.x; Xs[xj + 1][xi] = xv.y;
        Xs[xj + 2][xi] = xv.z; Xs[xj + 3][xi] = xv.w;
        // stage W tile 16x64 (coalesced rows)
        #pragma unroll
        for (int r = 0; r < 4; ++r)
            Ws[wj + r * 4][wi] = W[(size_t)(k0 + wj + r * 4) * N + n0 + wi];
        __syncthreads();

        #pragma unroll
        for (int kk = 0; kk < 16; ++kk) {
            float4 a = *(const float4*)&Xs[kk][ty * 4];
            float4 b = *(const float4*)&Ws[kk][tx * 4];
            acc[0][0] += a.x * b.x; acc[0][1] += a.x * b.y; acc[0][2] += a.x * b.z; acc[0][3] += a.x * b.w;
            acc[1][0] += a.y * b.x; acc[1][1] += a.y * b.y; acc[1][2] += a.y * b.z; acc[1][3] += a.y * b.w;
            acc[2][0] += a.z * b.x; acc[2][1] += a.z * b.y; acc[2][2] += a.z * b.z; acc[2][3] += a.z * b.w;
            acc[3][0] += a.w * b.x; acc[3][1] += a.w * b.y; acc[3][2] += a.w * b.z; acc[3][3] += a.w * b.w;
        }
        __syncthreads();
    }

    const int nb = n0 + tx * 4;
    float4 bv = *(const float4*)(bias + nb);
    #pragma unroll
    for (int ii = 0; ii < 4; ++ii) {
        int m = m0 + ty * 4 + ii;
        float4 v;
        v.x = acc[ii][0] + bv.x;
        v.y = acc[ii][1] + bv.y;
        v.z = acc[ii][2] + bv.z;
        v.w = acc[ii][3] + bv.w;
        if (split) {
            int b = m >> 11;          // m / S (S=2048)
            int s = m & 2047;
            int h = nb >> 6;          // n / D (D=64)
            int d = nb & 63;
            *(float4*)(Y + (((size_t)b * Hd + h) * Sd + s) * Dd + d) = v;
        } else {
            *(float4*)(Y + (size_t)m * N + nb) = v;
        }
    }
}

// ---------------------------------------------------------------------------
// Flash-style causal attention.  One block per (b*H+h, 64-row Q tile).
// 256 threads: thread t owns S-row i=t>>2 and 16 score-cols / 16 out-cols
// (group qg=t&3).  Online softmax (running m,l per row, replicated over the
// 4 lanes of a row; reductions via __shfl_xor over lanes {1,2}).
// Writes concat layout [B,S,E] (s, h*64+c).
// ---------------------------------------------------------------------------
__global__ __launch_bounds__(256) void attn_fwd_k(
    const float* __restrict__ Qh, const float* __restrict__ Kh,
    const float* __restrict__ Vh, float* __restrict__ Aout)
{
    __shared__ float Qs[64][68];
    __shared__ float Ks[64][68];
    __shared__ float Vs[64][68];
    __shared__ float Ps[64][68];

    const int tid = threadIdx.x;
    const int qt  = blockIdx.x;       // 0..31 Q tile
    const int bh  = blockIdx.y;       // 0..31 = b*H+h
    const int b   = bh >> 4;
    const int h   = bh & 15;

    // load Q tile (64 rows x 64 d, contiguous)
    const float4* Qb4 = (const float4*)(Qh + ((size_t)bh * Sd + qt * 64) * Dd);
    #pragma unroll
    for (int r = 0; r < 4; ++r) {
        int idx = r * 256 + tid;                 // float4 index, 1024 total
        int row = idx >> 4, col = (idx & 15) * 4;
        float4 v = Qb4[idx];
        Qs[row][col + 0] = v.x; Qs[row][col + 1] = v.y;
        Qs[row][col + 2] = v.z; Qs[row][col + 3] = v.w;
    }

    const int i     = tid >> 2;       // my S-row in tile
    const int qg    = tid & 3;
    const int jbase = qg * 16;        // my 16 score cols / out cols
    const int iglob = qt * 64 + i;

    float m_run = -1e30f, l_run = 0.f;
    float4 O0 = {0,0,0,0}, O1 = {0,0,0,0}, O2 = {0,0,0,0}, O3 = {0,0,0,0};

    __syncthreads();
    // hoist my Q row into registers (64 VGPRs, halves score-loop LDS traffic)
    float qreg[64];
    #pragma unroll
    for (int d4 = 0; d4 < 16; ++d4) {
        float4 v = *(const float4*)&Qs[i][d4 * 4];
        qreg[d4*4+0] = v.x; qreg[d4*4+1] = v.y; qreg[d4*4+2] = v.z; qreg[d4*4+3] = v.w;
    }

    for (int kt = 0; kt <= qt; ++kt) {
        __syncthreads();   // protect Ks/Vs/Ps from previous iteration readers
        const float4* Kb4 = (const float4*)(Kh + ((size_t)bh * Sd + kt * 64) * Dd);
        const float4* Vb4 = (const float4*)(Vh + ((size_t)bh * Sd + kt * 64) * Dd);
        #pragma unroll
        for (int r = 0; r < 4; ++r) {
            int idx = r * 256 + tid;
            int row = idx >> 4, col = (idx & 15) * 4;
            float4 kv = Kb4[idx];
            Ks[row][col + 0] = kv.x; Ks[row][col + 1] = kv.y;
            Ks[row][col + 2] = kv.z; Ks[row][col + 3] = kv.w;
            float4 vv = Vb4[idx];
            Vs[row][col + 0] = vv.x; Vs[row][col + 1] = vv.y;
            Vs[row][col + 2] = vv.z; Vs[row][col + 3] = vv.w;
        }
        __syncthreads();

        // scores for my 16 j's
        float p[16];
        float tmax = -1e30f;
        #pragma unroll
        for (int jj = 0; jj < 16; ++jj) {
            int j = jbase + jj;
            const float4* krow = (const float4*)&Ks[j][0];
            float s = 0.f;
            #pragma unroll
            for (int d4 = 0; d4 < 16; ++d4) {
                float4 kk4 = krow[d4];
                s += qreg[d4*4+0] * kk4.x + qreg[d4*4+1] * kk4.y
                   + qreg[d4*4+2] * kk4.z + qreg[d4*4+3] * kk4.w;
            }
            s *= 0.125f;                       // 1/sqrt(64)
            if (kt * 64 + j > iglob) s = -1e30f;   // causal mask
            p[jj] = s;
            tmax  = fmaxf(tmax, s);
        }
        // row max across the 4 lanes of this row
        tmax = fmaxf(tmax, __shfl_xor(tmax, 1));
        tmax = fmaxf(tmax, __shfl_xor(tmax, 2));
        float m_new = fmaxf(m_run, tmax);

        float rsum = 0.f;
        #pragma unroll
        for (int jj = 0; jj < 16; ++jj) {
            p[jj] = __expf(p[jj] - m_new);     // masked -> exp(-huge) = 0
            rsum += p[jj];
        }
        rsum += __shfl_xor(rsum, 1);
        rsum += __shfl_xor(rsum, 2);

        float alpha = __expf(m_run - m_new);
        m_run = m_new;
        l_run = l_run * alpha + rsum;
        O0.x *= alpha; O0.y *= alpha; O0.z *= alpha; O0.w *= alpha;
        O1.x *= alpha; O1.y *= alpha; O1.z *= alpha; O1.w *= alpha;
        O2.x *= alpha; O2.y *= alpha; O2.z *= alpha; O2.w *= alpha;
        O3.x *= alpha; O3.y *= alpha; O3.z *= alpha; O3.w *= alpha;

        // stage P row
        *(float4*)&Ps[i][jbase + 0]  = make_float4(p[0],  p[1],  p[2],  p[3]);
        *(float4*)&Ps[i][jbase + 4]  = make_float4(p[4],  p[5],  p[6],  p[7]);
        *(float4*)&Ps[i][jbase + 8]  = make_float4(p[8],  p[9],  p[10], p[11]);
        *(float4*)&Ps[i][jbase + 12] = make_float4(p[12], p[13], p[14], p[15]);
        __syncthreads();

        // O += P @ V  (my 16 out cols = jbase..jbase+15)
        #pragma unroll
        for (int j = 0; j < 64; ++j) {
            float pj = Ps[i][j];
            const float4* vrow = (const float4*)&Vs[j][jbase];
            float4 v0 = vrow[0], v1 = vrow[1], v2 = vrow[2], v3 = vrow[3];
            O0.x += pj * v0.x; O0.y += pj * v0.y; O0.z += pj * v0.z; O0.w += pj * v0.w;
            O1.x += pj * v1.x; O1.y += pj * v1.y; O1.z += pj * v1.z; O1.w += pj * v1.w;
            O2.x += pj * v2.x; O2.y += pj * v2.y; O2.z += pj * v2.z; O2.w += pj * v2.w;
            O3.x += pj * v3.x; O3.y += pj * v3.y; O3.z += pj * v3.z; O3.w += pj * v3.w;
        }
    }

    float inv = 1.f / l_run;
    O0.x *= inv; O0.y *= inv; O0.z *= inv; O0.w *= inv;
    O1.x *= inv; O1.y *= inv; O1.z *= inv; O1.w *= inv;
    O2.x *= inv; O2.y *= inv; O2.z *= inv; O2.w *= inv;
    O3.x *= inv; O3.y *= inv; O3.z *= inv; O3.w *= inv;

    float* outp = Aout + ((size_t)b * Sd + iglob) * Ed + h * Dd + jbase;
    ((float4*)outp)[0] = O0;
    ((float4*)outp)[1] = O1;
    ((float4*)outp)[2] = O2;
    ((float4*)outp)[3] = O3;
}

// ---------------------------------------------------------------------------
extern "C" void kernel_launch(void* const* d_in, const int* in_sizes, int n_in,
                              void* d_out, int out_size, void* d_ws, size_t ws_size,
                              hipStream_t stream) {
    const float* q  = (const float*)d_in[0];
    const float* k  = (const float*)d_in[1];
    const float* v  = (const float*)d_in[2];
    const float* Wq = (const float*)d_in[3];
    const float* bq = (const float*)d_in[4];
    const float* Wk = (const float*)d_in[5];
    const float* bk = (const float*)d_in[6];
    const float* Wv = (const float*)d_in[7];
    const float* bv = (const float*)d_in[8];
    const float* Wo = (const float*)d_in[9];
    const float* bo = (const float*)d_in[10];

    float* ws = (float*)d_ws;
    const size_t TENS = (size_t)Bd * Sd * Ed;   // 4,194,304 elements (16 MB)
    float* Qh = ws;
    float* Kh = ws + TENS;
    float* Vh = ws + 2 * TENS;
    float* An = ws + 3 * TENS;

    const int M = Bd * Sd;   // 4096
    const int N = Ed;        // 1024
    const int K = Ed;        // 1024
    dim3 ggrid(N / 64, M / 64);   // 16 x 64

    gemm_bias_k<<<ggrid, 256, 0, stream>>>(q, Wq, bq, Qh, M, N, K, 1);
    gemm_bias_k<<<ggrid, 256, 0, stream>>>(k, Wk, bk, Kh, M, N, K, 1);
    gemm_bias_k<<<ggrid, 256, 0, stream>>>(v, Wv, bv, Vh, M, N, K, 1);

    attn_fwd_k<<<dim3(Sd / 64, Bd * Hd), 256, 0, stream>>>(Qh, Kh, Vh, An);

    gemm_bias_k<<<ggrid, 256, 0, stream>>>(An, Wo, bo, (float*)d_out, M, N, K, 0);
}

// Round 2
// 782.325 us; speedup vs baseline: 2.4247x; 2.4247x over previous
//
#include <hip/hip_runtime.h>
#include <math.h>

#define Bd 2
#define Sd 2048
#define Ed 1024
#define Hd 16
#define Dd 64

typedef __attribute__((ext_vector_type(8))) short bf16x8;
typedef __attribute__((ext_vector_type(4))) float f32x4;

__device__ __forceinline__ unsigned short f2bf(float f) {
    unsigned x = __float_as_uint(f);
    x += 0x7fffu + ((x >> 16) & 1u);
    return (unsigned short)(x >> 16);
}

// ---------------------------------------------------------------------------
// GEMM: Y = (X @ W + bias) * oscale.  X:[M,K] fp32 row-major, W:[K,N] fp32.
// mode 0: fp32 flat [M,N]
// mode 1: bf16 head-split [B,H,S,D]
// mode 2: bf16 head-split TRANSPOSED [B,H,D,S]  (for V)
// ---------------------------------------------------------------------------
__global__ __launch_bounds__(256) void gemm_bias_k(
    const float* __restrict__ X, const float* __restrict__ W,
    const float* __restrict__ bias, void* __restrict__ Yv,
    int M, int N, int K, int mode, float oscale)
{
    __shared__ float Xs[16][68];
    __shared__ float Ws[16][64];

    const int tid = threadIdx.x;
    const int m0 = blockIdx.y * 64;
    const int n0 = blockIdx.x * 64;
    const int tx = tid & 15, ty = tid >> 4;

    const int xi = tid >> 2;
    const int xj = (tid & 3) * 4;
    const int wj = tid >> 6;
    const int wi = tid & 63;

    float acc[4][4] = {{0.f}};

    for (int k0 = 0; k0 < K; k0 += 16) {
        float4 xv = *(const float4*)(X + (size_t)(m0 + xi) * K + k0 + xj);
        Xs[xj + 0][xi] = xv.x; Xs[xj + 1][xi] = xv.y;
        Xs[xj + 2][xi] = xv.z; Xs[xj + 3][xi] = xv.w;
        #pragma unroll
        for (int r = 0; r < 4; ++r)
            Ws[wj + r * 4][wi] = W[(size_t)(k0 + wj + r * 4) * N + n0 + wi];
        __syncthreads();

        #pragma unroll
        for (int kk = 0; kk < 16; ++kk) {
            float4 a = *(const float4*)&Xs[kk][ty * 4];
            float4 b = *(const float4*)&Ws[kk][tx * 4];
            acc[0][0] += a.x * b.x; acc[0][1] += a.x * b.y; acc[0][2] += a.x * b.z; acc[0][3] += a.x * b.w;
            acc[1][0] += a.y * b.x; acc[1][1] += a.y * b.y; acc[1][2] += a.y * b.z; acc[1][3] += a.y * b.w;
            acc[2][0] += a.z * b.x; acc[2][1] += a.z * b.y; acc[2][2] += a.z * b.z; acc[2][3] += a.z * b.w;
            acc[3][0] += a.w * b.x; acc[3][1] += a.w * b.y; acc[3][2] += a.w * b.z; acc[3][3] += a.w * b.w;
        }
        __syncthreads();
    }

    const int nb = n0 + tx * 4;
    float4 bv = *(const float4*)(bias + nb);
    float vv[4][4];
    #pragma unroll
    for (int ii = 0; ii < 4; ++ii) {
        vv[ii][0] = (acc[ii][0] + bv.x) * oscale;
        vv[ii][1] = (acc[ii][1] + bv.y) * oscale;
        vv[ii][2] = (acc[ii][2] + bv.z) * oscale;
        vv[ii][3] = (acc[ii][3] + bv.w) * oscale;
    }

    if (mode == 0) {
        float* Y = (float*)Yv;
        #pragma unroll
        for (int ii = 0; ii < 4; ++ii) {
            int m = m0 + ty * 4 + ii;
            *(float4*)(Y + (size_t)m * N + nb) =
                make_float4(vv[ii][0], vv[ii][1], vv[ii][2], vv[ii][3]);
        }
    } else if (mode == 1) {
        unsigned short* Y = (unsigned short*)Yv;
        const int h = nb >> 6, d = nb & 63;
        #pragma unroll
        for (int ii = 0; ii < 4; ++ii) {
            int m = m0 + ty * 4 + ii;
            int b = m >> 11, s = m & 2047;
            ushort4 u = make_ushort4(f2bf(vv[ii][0]), f2bf(vv[ii][1]),
                                     f2bf(vv[ii][2]), f2bf(vv[ii][3]));
            *(ushort4*)(Y + (((size_t)b * Hd + h) * Sd + s) * Dd + d) = u;
        }
    } else {
        unsigned short* Y = (unsigned short*)Yv;
        const int h = nb >> 6, d0 = nb & 63;
        const int b = m0 >> 11;
        const int s0 = (m0 & 2047) + ty * 4;
        #pragma unroll
        for (int j = 0; j < 4; ++j) {
            ushort4 u = make_ushort4(f2bf(vv[0][j]), f2bf(vv[1][j]),
                                     f2bf(vv[2][j]), f2bf(vv[3][j]));
            *(ushort4*)(Y + (((size_t)b * Hd + h) * Dd + d0 + j) * Sd + s0) = u;
        }
    }
}

// ---------------------------------------------------------------------------
// Flash-style causal attention on MFMA bf16 16x16x32.
// Block = 4 waves; wave w owns 16 q rows.  Block processes q-tile pair
// {x, 31-x} -> constant 33 kt-iterations (perfect causal load balance).
// Per kt tile (64 keys):
//   S^T = K @ Q^T   (A=K rows, B=Q rows; C layout: row=key, col=q)
//   online softmax in registers (reduce over quad groups: shfl_xor 16,32)
//   P^T -> LDS (bf16, padded row 72) -> B-fragments
//   O^T += V^T @ P^T  (V stored [B,H,D,S] so V^T rows are contiguous)
// Barrier-free: all LDS traffic is intra-wave (wave-synchronous).
// ---------------------------------------------------------------------------
__global__ __launch_bounds__(256) void attn_mfma_k(
    const unsigned short* __restrict__ Qg,   // [B,H,S,D] bf16, pre-scaled 1/8
    const unsigned short* __restrict__ Kg,   // [B,H,S,D] bf16
    const unsigned short* __restrict__ Vg,   // [B,H,D,S] bf16
    float* __restrict__ Aout)                // [B,S,E] fp32
{
    __shared__ unsigned short Pt[4][16][72];   // per-wave P^T slab, 2-way max

    const int tid  = threadIdx.x;
    const int w    = tid >> 6;
    const int lane = tid & 63;
    const int ln   = lane & 15;     // q column (n index)
    const int quad = lane >> 4;     // 0..3
    const int bh   = blockIdx.y;
    const int b    = bh >> 4;
    const int h    = bh & 15;

    const size_t baseQK = (size_t)bh * Sd * Dd;
    const size_t baseV  = (size_t)bh * Dd * Sd;

    const f32x4 vzero = {0.f, 0.f, 0.f, 0.f};

    for (int half = 0; half < 2; ++half) {
        const int qt   = half ? (31 - (int)blockIdx.x) : (int)blockIdx.x;
        const int qrow = qt * 64 + w * 16;

        // Q fragments for this wave's 16 rows (kept in VGPRs for all kt)
        const unsigned short* qp = Qg + baseQK + (size_t)(qrow + ln) * Dd + 8 * quad;
        bf16x8 qf0 = *(const bf16x8*)(qp);
        bf16x8 qf1 = *(const bf16x8*)(qp + 32);

        float m_run = -1e30f, l_run = 0.f;
        f32x4 O[4];
        #pragma unroll
        for (int t = 0; t < 4; ++t) O[t] = vzero;

        for (int kt = 0; kt <= qt; ++kt) {
            const int krow = kt * 64;

            // ---- scores S^T = K @ Q^T ----
            f32x4 S[4];
            #pragma unroll
            for (int t = 0; t < 4; ++t) {
                const unsigned short* kp =
                    Kg + baseQK + (size_t)(krow + t * 16 + ln) * Dd + 8 * quad;
                bf16x8 k0 = *(const bf16x8*)(kp);
                bf16x8 k1 = *(const bf16x8*)(kp + 32);
                f32x4 z = __builtin_amdgcn_mfma_f32_16x16x32_bf16(k0, qf0, vzero, 0, 0, 0);
                S[t]     = __builtin_amdgcn_mfma_f32_16x16x32_bf16(k1, qf1, z,     0, 0, 0);
            }

            // ---- online softmax (per q column = per lane group) ----
            const bool diag = (kt == qt);
            float tmax = -1e30f;
            #pragma unroll
            for (int t = 0; t < 4; ++t) {
                #pragma unroll
                for (int r = 0; r < 4; ++r) {
                    if (diag && (t * 16 + quad * 4 + r > w * 16 + ln))
                        S[t][r] = -1e30f;            // causal mask
                    tmax = fmaxf(tmax, S[t][r]);
                }
            }
            tmax = fmaxf(tmax, __shfl_xor(tmax, 16));
            tmax = fmaxf(tmax, __shfl_xor(tmax, 32));
            float m_new = fmaxf(m_run, tmax);

            float p[16];
            float rsum = 0.f;
            #pragma unroll
            for (int t = 0; t < 4; ++t) {
                #pragma unroll
                for (int r = 0; r < 4; ++r) {
                    float e = __expf(S[t][r] - m_new);
                    p[t * 4 + r] = e;
                    rsum += e;
                }
            }
            rsum += __shfl_xor(rsum, 16);
            rsum += __shfl_xor(rsum, 32);

            float alpha = __expf(m_run - m_new);
            m_run = m_new;
            l_run = l_run * alpha + rsum;
            #pragma unroll
            for (int t = 0; t < 4; ++t) {
                O[t][0] *= alpha; O[t][1] *= alpha;
                O[t][2] *= alpha; O[t][3] *= alpha;
            }

            // ---- P^T to LDS (bf16), then B-fragments ----
            #pragma unroll
            for (int t = 0; t < 4; ++t) {
                ushort4 u = make_ushort4(f2bf(p[t * 4 + 0]), f2bf(p[t * 4 + 1]),
                                         f2bf(p[t * 4 + 2]), f2bf(p[t * 4 + 3]));
                *(ushort4*)&Pt[w][ln][t * 16 + quad * 4] = u;
            }
            bf16x8 pf0 = *(const bf16x8*)&Pt[w][ln][8 * quad];
            bf16x8 pf1 = *(const bf16x8*)&Pt[w][ln][32 + 8 * quad];

            // ---- O^T += V^T @ P^T ----
            #pragma unroll
            for (int t = 0; t < 4; ++t) {
                const unsigned short* vp =
                    Vg + baseV + (size_t)(t * 16 + ln) * Sd + krow + 8 * quad;
                bf16x8 v0 = *(const bf16x8*)(vp);
                bf16x8 v1 = *(const bf16x8*)(vp + 32);
                O[t] = __builtin_amdgcn_mfma_f32_16x16x32_bf16(v0, pf0, O[t], 0, 0, 0);
                O[t] = __builtin_amdgcn_mfma_f32_16x16x32_bf16(v1, pf1, O[t], 0, 0, 0);
            }
        }

        // ---- epilogue: O[q][d] = O^T / l, write concat [B,S,E] ----
        float inv = 1.f / l_run;
        float* op = Aout + ((size_t)b * Sd + qrow + ln) * Ed + h * 64 + quad * 4;
        #pragma unroll
        for (int t = 0; t < 4; ++t) {
            float4 o4 = make_float4(O[t][0] * inv, O[t][1] * inv,
                                    O[t][2] * inv, O[t][3] * inv);
            *(float4*)(op + t * 16) = o4;
        }
    }
}

// ---------------------------------------------------------------------------
extern "C" void kernel_launch(void* const* d_in, const int* in_sizes, int n_in,
                              void* d_out, int out_size, void* d_ws, size_t ws_size,
                              hipStream_t stream) {
    const float* q  = (const float*)d_in[0];
    const float* k  = (const float*)d_in[1];
    const float* v  = (const float*)d_in[2];
    const float* Wq = (const float*)d_in[3];
    const float* bq = (const float*)d_in[4];
    const float* Wk = (const float*)d_in[5];
    const float* bk = (const float*)d_in[6];
    const float* Wv = (const float*)d_in[7];
    const float* bv = (const float*)d_in[8];
    const float* Wo = (const float*)d_in[9];
    const float* bo = (const float*)d_in[10];

    const size_t TENS = (size_t)Bd * Sd * Ed;          // 4,194,304 elements
    unsigned short* Qh = (unsigned short*)d_ws;        //  8 MB bf16
    unsigned short* Kh = Qh + TENS;                    //  8 MB bf16
    unsigned short* Vt = Kh + TENS;                    //  8 MB bf16 [B,H,D,S]
    float* An = (float*)((char*)d_ws + 3 * TENS * sizeof(unsigned short)); // 16 MB fp32

    const int M = Bd * Sd;   // 4096
    const int N = Ed;        // 1024
    const int K = Ed;        // 1024
    dim3 ggrid(N / 64, M / 64);

    // Q pre-scaled by 1/sqrt(D)=0.125 so attention needs no score scaling
    gemm_bias_k<<<ggrid, 256, 0, stream>>>(q, Wq, bq, Qh, M, N, K, 1, 0.125f);
    gemm_bias_k<<<ggrid, 256, 0, stream>>>(k, Wk, bk, Kh, M, N, K, 1, 1.0f);
    gemm_bias_k<<<ggrid, 256, 0, stream>>>(v, Wv, bv, Vt, M, N, K, 2, 1.0f);

    attn_mfma_k<<<dim3(16, Bd * Hd), 256, 0, stream>>>(Qh, Kh, Vt, An);

    gemm_bias_k<<<ggrid, 256, 0, stream>>>(An, Wo, bo, d_out, M, N, K, 0, 1.0f);
}

// Round 3
// 320.178 us; speedup vs baseline: 5.9245x; 2.4434x over previous
//
#include <hip/hip_runtime.h>
#include <math.h>

#define Bd 2
#define Sd 2048
#define Ed 1024
#define Hd 16
#define Dd 64
#define Md (Bd * Sd)     // 4096
#define Kd 1024          // GEMM K == E
#define Nd 1024          // GEMM N == E

typedef __attribute__((ext_vector_type(8))) short bf16x8;
typedef __attribute__((ext_vector_type(4))) float f32x4;

__device__ __forceinline__ unsigned short f2bf(float f) {
    unsigned x = __float_as_uint(f);
    x += 0x7fffu + ((x >> 16) & 1u);
    return (unsigned short)(x >> 16);
}

__device__ __forceinline__ void gl2lds16(const unsigned short* g, unsigned short* l) {
    // 16B-per-lane async global->LDS (global_load_lds_dwordx4).
    // LDS dest is wave-uniform base + lane*16 — layout must be lane-contiguous.
    __builtin_amdgcn_global_load_lds(
        (__attribute__((address_space(1))) void*)g,
        (__attribute__((address_space(3))) void*)l, 16, 0, 0);
}

// ---------------------------------------------------------------------------
// Fused fp32->bf16 convert for q,k,v (grid.y selects tensor)
// ---------------------------------------------------------------------------
__global__ __launch_bounds__(256) void cvt3_k(
    const float* __restrict__ a, const float* __restrict__ b, const float* __restrict__ c,
    unsigned short* __restrict__ da, unsigned short* __restrict__ db,
    unsigned short* __restrict__ dc, int n4)
{
    const float* s = blockIdx.y == 0 ? a : blockIdx.y == 1 ? b : c;
    unsigned short* d = blockIdx.y == 0 ? da : blockIdx.y == 1 ? db : dc;
    int i = blockIdx.x * blockDim.x + threadIdx.x;
    int stride = gridDim.x * blockDim.x;
    for (; i < n4; i += stride) {
        float4 v = ((const float4*)s)[i];
        ushort4 u = make_ushort4(f2bf(v.x), f2bf(v.y), f2bf(v.z), f2bf(v.w));
        ((ushort4*)d)[i] = u;
    }
}

// ---------------------------------------------------------------------------
// Fused weight transpose+convert: W[K,N] fp32 -> Wt[N,K] bf16 (grid.z = 4)
// ---------------------------------------------------------------------------
__global__ __launch_bounds__(256) void wtrans_k(
    const float* __restrict__ w0, const float* __restrict__ w1,
    const float* __restrict__ w2, const float* __restrict__ w3,
    unsigned short* __restrict__ o0, unsigned short* __restrict__ o1,
    unsigned short* __restrict__ o2, unsigned short* __restrict__ o3)
{
    __shared__ unsigned short Tl[32][36];
    const int z = blockIdx.z;
    const float* W = z == 0 ? w0 : z == 1 ? w1 : z == 2 ? w2 : w3;
    unsigned short* Wt = z == 0 ? o0 : z == 1 ? o1 : z == 2 ? o2 : o3;

    const int t = threadIdx.x;
    const int r = t >> 3;            // 0..31
    const int c4 = (t & 7) * 4;      // 0..28
    const int k0 = blockIdx.y * 32;
    const int n0 = blockIdx.x * 32;

    float4 v = *(const float4*)(W + (size_t)(k0 + r) * Nd + n0 + c4);
    Tl[c4 + 0][r] = f2bf(v.x);
    Tl[c4 + 1][r] = f2bf(v.y);
    Tl[c4 + 2][r] = f2bf(v.z);
    Tl[c4 + 3][r] = f2bf(v.w);
    __syncthreads();
    ushort4 u = make_ushort4(Tl[r][c4 + 0], Tl[r][c4 + 1], Tl[r][c4 + 2], Tl[r][c4 + 3]);
    *(ushort4*)(Wt + (size_t)(n0 + r) * Kd + k0 + c4) = u;
}

// ---------------------------------------------------------------------------
// bf16 MFMA GEMM body (m97 structure): C = A @ Bt^T (+bias)*oscale
// A:[M,K] bf16 row-major, Bt:[N,K] bf16 row-major. 128x128 tile, BK=32,
// 4 waves in 2x2, each wave 64x64 via 4x4 of 16x16x32 MFMA.
// mode 0: fp32 flat [M,N];  mode 1: bf16 [B,H,S,D];  mode 2: bf16 [B,H,D,S]
// ---------------------------------------------------------------------------
__device__ __forceinline__ void gemm_mfma_body(
    const unsigned short* __restrict__ A, const unsigned short* __restrict__ Bt,
    const float* __restrict__ bias, void* __restrict__ Yv, int mode, float oscale)
{
    __shared__ unsigned short As[128 * 32];
    __shared__ unsigned short Bs[128 * 32];

    const int tid  = threadIdx.x;
    const int w    = tid >> 6;
    const int lane = tid & 63;
    const int ln   = lane & 15;
    const int quad = lane >> 4;
    const int m0 = blockIdx.y * 128;
    const int n0 = blockIdx.x * 128;
    const int wm = (w >> 1) * 64;
    const int wn = (w & 1) * 64;

    // staging: 8 segments of 16 rows x 32 cols; wave w owns segs {2w, 2w+1}
    const int seg  = w * 2;
    const int lrow = lane >> 2;        // 0..15
    const int lcol = (lane & 3) * 8;   // bf16 col offset

    const unsigned short* Ag0 = A  + (size_t)(m0 + seg * 16 + lrow) * Kd + lcol;
    const unsigned short* Ag1 = Ag0 + 16 * Kd;
    const unsigned short* Bg0 = Bt + (size_t)(n0 + seg * 16 + lrow) * Kd + lcol;
    const unsigned short* Bg1 = Bg0 + 16 * Kd;
    unsigned short* Al0 = As + seg * 16 * 32;
    unsigned short* Al1 = Al0 + 16 * 32;
    unsigned short* Bl0 = Bs + seg * 16 * 32;
    unsigned short* Bl1 = Bl0 + 16 * 32;

    f32x4 acc[4][4];
    #pragma unroll
    for (int i = 0; i < 4; ++i)
        #pragma unroll
        for (int j = 0; j < 4; ++j)
            acc[i][j] = (f32x4){0.f, 0.f, 0.f, 0.f};

    for (int k0 = 0; k0 < Kd; k0 += 32) {
        __syncthreads();               // protect LDS from prev-iter readers
        gl2lds16(Ag0 + k0, Al0);
        gl2lds16(Ag1 + k0, Al1);
        gl2lds16(Bg0 + k0, Bl0);
        gl2lds16(Bg1 + k0, Bl1);
        __syncthreads();               // drains vmcnt(0): staging complete

        bf16x8 af[4], bfr[4];
        #pragma unroll
        for (int mi = 0; mi < 4; ++mi)
            af[mi] = *(const bf16x8*)(As + (wm + mi * 16 + ln) * 32 + quad * 8);
        #pragma unroll
        for (int ni = 0; ni < 4; ++ni)
            bfr[ni] = *(const bf16x8*)(Bs + (wn + ni * 16 + ln) * 32 + quad * 8);
        #pragma unroll
        for (int mi = 0; mi < 4; ++mi)
            #pragma unroll
            for (int ni = 0; ni < 4; ++ni)
                acc[mi][ni] = __builtin_amdgcn_mfma_f32_16x16x32_bf16(
                    af[mi], bfr[ni], acc[mi][ni], 0, 0, 0);
    }

    // epilogue.  C layout: row m = quad*4 + reg, col n = ln (per 16x16 tile)
    float bval[4];
    #pragma unroll
    for (int ni = 0; ni < 4; ++ni) bval[ni] = bias[n0 + wn + ni * 16 + ln];

    if (mode == 0) {
        float* Y = (float*)Yv;
        #pragma unroll
        for (int mi = 0; mi < 4; ++mi) {
            #pragma unroll
            for (int ni = 0; ni < 4; ++ni) {
                int n = n0 + wn + ni * 16 + ln;
                #pragma unroll
                for (int r = 0; r < 4; ++r) {
                    int m = m0 + wm + mi * 16 + quad * 4 + r;
                    Y[(size_t)m * Nd + n] = (acc[mi][ni][r] + bval[ni]) * oscale;
                }
            }
        }
    } else if (mode == 1) {
        unsigned short* Y = (unsigned short*)Yv;
        #pragma unroll
        for (int mi = 0; mi < 4; ++mi) {
            #pragma unroll
            for (int ni = 0; ni < 4; ++ni) {
                int n = n0 + wn + ni * 16 + ln;
                int h = n >> 6, d = n & 63;
                #pragma unroll
                for (int r = 0; r < 4; ++r) {
                    int m = m0 + wm + mi * 16 + quad * 4 + r;
                    int b = m >> 11, s = m & 2047;
                    Y[(((size_t)b * Hd + h) * Sd + s) * Dd + d] =
                        f2bf((acc[mi][ni][r] + bval[ni]) * oscale);
                }
            }
        }
    } else {
        unsigned short* Y = (unsigned short*)Yv;
        #pragma unroll
        for (int mi = 0; mi < 4; ++mi) {
            int mbase = m0 + wm + mi * 16 + quad * 4;
            int b = mbase >> 11, s = mbase & 2047;
            #pragma unroll
            for (int ni = 0; ni < 4; ++ni) {
                int n = n0 + wn + ni * 16 + ln;
                int h = n >> 6, d = n & 63;
                ushort4 u = make_ushort4(
                    f2bf((acc[mi][ni][0] + bval[ni]) * oscale),
                    f2bf((acc[mi][ni][1] + bval[ni]) * oscale),
                    f2bf((acc[mi][ni][2] + bval[ni]) * oscale),
                    f2bf((acc[mi][ni][3] + bval[ni]) * oscale));
                *(ushort4*)(Y + (((size_t)b * Hd + h) * Dd + d) * Sd + s) = u;
            }
        }
    }
}

// Fused Q/K/V projection: grid.z picks the matmul. 768 blocks = 3/CU.
__global__ __launch_bounds__(256) void proj_gemm_k(
    const unsigned short* A0, const unsigned short* A1, const unsigned short* A2,
    const unsigned short* B0, const unsigned short* B1, const unsigned short* B2,
    const float* b0, const float* b1, const float* b2,
    unsigned short* Y0, unsigned short* Y1, unsigned short* Y2)
{
    const int z = blockIdx.z;
    const unsigned short* A = z == 0 ? A0 : z == 1 ? A1 : A2;
    const unsigned short* B = z == 0 ? B0 : z == 1 ? B1 : B2;
    const float* bias       = z == 0 ? b0 : z == 1 ? b1 : b2;
    unsigned short* Y       = z == 0 ? Y0 : z == 1 ? Y1 : Y2;
    gemm_mfma_body(A, B, bias, Y, z == 2 ? 2 : 1, z == 0 ? 0.125f : 1.0f);
}

__global__ __launch_bounds__(256) void out_gemm_k(
    const unsigned short* A, const unsigned short* Bt, const float* bias, float* Y)
{
    gemm_mfma_body(A, Bt, bias, Y, 0, 1.0f);
}

// ---------------------------------------------------------------------------
// Flash-style causal attention on MFMA bf16 16x16x32 (unchanged from r2
// except bf16 output).  Block = 4 waves; processes q-tile pair {x, 31-x}.
// ---------------------------------------------------------------------------
__global__ __launch_bounds__(256) void attn_mfma_k(
    const unsigned short* __restrict__ Qg,   // [B,H,S,D] bf16, pre-scaled 1/8
    const unsigned short* __restrict__ Kg,   // [B,H,S,D] bf16
    const unsigned short* __restrict__ Vg,   // [B,H,D,S] bf16
    unsigned short* __restrict__ Aout)       // [B,S,E] bf16
{
    __shared__ unsigned short Pt[4][16][72];

    const int tid  = threadIdx.x;
    const int w    = tid >> 6;
    const int lane = tid & 63;
    const int ln   = lane & 15;
    const int quad = lane >> 4;
    const int bh   = blockIdx.y;
    const int b    = bh >> 4;
    const int h    = bh & 15;

    const size_t baseQK = (size_t)bh * Sd * Dd;
    const size_t baseV  = (size_t)bh * Dd * Sd;
    const f32x4 vzero = {0.f, 0.f, 0.f, 0.f};

    for (int half = 0; half < 2; ++half) {
        const int qt   = half ? (31 - (int)blockIdx.x) : (int)blockIdx.x;
        const int qrow = qt * 64 + w * 16;

        const unsigned short* qp = Qg + baseQK + (size_t)(qrow + ln) * Dd + 8 * quad;
        bf16x8 qf0 = *(const bf16x8*)(qp);
        bf16x8 qf1 = *(const bf16x8*)(qp + 32);

        float m_run = -1e30f, l_run = 0.f;
        f32x4 O[4];
        #pragma unroll
        for (int t = 0; t < 4; ++t) O[t] = vzero;

        for (int kt = 0; kt <= qt; ++kt) {
            const int krow = kt * 64;

            f32x4 S[4];
            #pragma unroll
            for (int t = 0; t < 4; ++t) {
                const unsigned short* kp =
                    Kg + baseQK + (size_t)(krow + t * 16 + ln) * Dd + 8 * quad;
                bf16x8 k0 = *(const bf16x8*)(kp);
                bf16x8 k1 = *(const bf16x8*)(kp + 32);
                f32x4 z = __builtin_amdgcn_mfma_f32_16x16x32_bf16(k0, qf0, vzero, 0, 0, 0);
                S[t]     = __builtin_amdgcn_mfma_f32_16x16x32_bf16(k1, qf1, z,     0, 0, 0);
            }

            const bool diag = (kt == qt);
            float tmax = -1e30f;
            #pragma unroll
            for (int t = 0; t < 4; ++t) {
                #pragma unroll
                for (int r = 0; r < 4; ++r) {
                    if (diag && (t * 16 + quad * 4 + r > w * 16 + ln))
                        S[t][r] = -1e30f;
                    tmax = fmaxf(tmax, S[t][r]);
                }
            }
            tmax = fmaxf(tmax, __shfl_xor(tmax, 16));
            tmax = fmaxf(tmax, __shfl_xor(tmax, 32));
            float m_new = fmaxf(m_run, tmax);

            float p[16];
            float rsum = 0.f;
            #pragma unroll
            for (int t = 0; t < 4; ++t) {
                #pragma unroll
                for (int r = 0; r < 4; ++r) {
                    float e = __expf(S[t][r] - m_new);
                    p[t * 4 + r] = e;
                    rsum += e;
                }
            }
            rsum += __shfl_xor(rsum, 16);
            rsum += __shfl_xor(rsum, 32);

            float alpha = __expf(m_run - m_new);
            m_run = m_new;
            l_run = l_run * alpha + rsum;
            #pragma unroll
            for (int t = 0; t < 4; ++t) {
                O[t][0] *= alpha; O[t][1] *= alpha;
                O[t][2] *= alpha; O[t][3] *= alpha;
            }

            #pragma unroll
            for (int t = 0; t < 4; ++t) {
                ushort4 u = make_ushort4(f2bf(p[t * 4 + 0]), f2bf(p[t * 4 + 1]),
                                         f2bf(p[t * 4 + 2]), f2bf(p[t * 4 + 3]));
                *(ushort4*)&Pt[w][ln][t * 16 + quad * 4] = u;
            }
            bf16x8 pf0 = *(const bf16x8*)&Pt[w][ln][8 * quad];
            bf16x8 pf1 = *(const bf16x8*)&Pt[w][ln][32 + 8 * quad];

            #pragma unroll
            for (int t = 0; t < 4; ++t) {
                const unsigned short* vp =
                    Vg + baseV + (size_t)(t * 16 + ln) * Sd + krow + 8 * quad;
                bf16x8 v0 = *(const bf16x8*)(vp);
                bf16x8 v1 = *(const bf16x8*)(vp + 32);
                O[t] = __builtin_amdgcn_mfma_f32_16x16x32_bf16(v0, pf0, O[t], 0, 0, 0);
                O[t] = __builtin_amdgcn_mfma_f32_16x16x32_bf16(v1, pf1, O[t], 0, 0, 0);
            }
        }

        float inv = 1.f / l_run;
        unsigned short* op = Aout + ((size_t)b * Sd + qrow + ln) * Ed + h * 64 + quad * 4;
        #pragma unroll
        for (int t = 0; t < 4; ++t) {
            ushort4 u = make_ushort4(f2bf(O[t][0] * inv), f2bf(O[t][1] * inv),
                                     f2bf(O[t][2] * inv), f2bf(O[t][3] * inv));
            *(ushort4*)(op + t * 16) = u;
        }
    }
}

// ---------------------------------------------------------------------------
extern "C" void kernel_launch(void* const* d_in, const int* in_sizes, int n_in,
                              void* d_out, int out_size, void* d_ws, size_t ws_size,
                              hipStream_t stream) {
    const float* q  = (const float*)d_in[0];
    const float* k  = (const float*)d_in[1];
    const float* v  = (const float*)d_in[2];
    const float* Wq = (const float*)d_in[3];
    const float* bq = (const float*)d_in[4];
    const float* Wk = (const float*)d_in[5];
    const float* bk = (const float*)d_in[6];
    const float* Wv = (const float*)d_in[7];
    const float* bv = (const float*)d_in[8];
    const float* Wo = (const float*)d_in[9];
    const float* bo = (const float*)d_in[10];

    const size_t TENS = (size_t)Bd * Sd * Ed;  // 4,194,304
    const size_t WE   = (size_t)Ed * Ed;       // 1,048,576
    unsigned short* W0 = (unsigned short*)d_ws;
    unsigned short* qb  = W0;                 // bf16 [M,K]
    unsigned short* kb  = qb + TENS;
    unsigned short* vb  = kb + TENS;
    unsigned short* Wqt = vb + TENS;          // bf16 [N,K]
    unsigned short* Wkt = Wqt + WE;
    unsigned short* Wvt = Wkt + WE;
    unsigned short* Wot = Wvt + WE;
    unsigned short* Qh  = Wot + WE;           // bf16 [B,H,S,D]
    unsigned short* Kh  = Qh + TENS;
    unsigned short* Vt  = Kh + TENS;          // bf16 [B,H,D,S]
    unsigned short* An  = Vt + TENS;          // bf16 [B,S,E]

    cvt3_k<<<dim3(1024, 3), 256, 0, stream>>>(q, k, v, qb, kb, vb, (int)(TENS / 4));
    wtrans_k<<<dim3(32, 32, 4), 256, 0, stream>>>(Wq, Wk, Wv, Wo, Wqt, Wkt, Wvt, Wot);
    proj_gemm_k<<<dim3(Nd / 128, Md / 128, 3), 256, 0, stream>>>(
        qb, kb, vb, Wqt, Wkt, Wvt, bq, bk, bv, Qh, Kh, Vt);
    attn_mfma_k<<<dim3(16, Bd * Hd), 256, 0, stream>>>(Qh, Kh, Vt, An);
    out_gemm_k<<<dim3(Nd / 128, Md / 128), 256, 0, stream>>>(An, Wot, bo, (float*)d_out);
}